// Round 1
// baseline (153.711 us; speedup 1.0000x reference)
//
#include <hip/hip_runtime.h>
#include <hip/hip_bf16.h>
#include <stdint.h>

typedef short bf16x8 __attribute__((ext_vector_type(8)));
typedef float f32x4  __attribute__((ext_vector_type(4)));

__device__ __forceinline__ short f2bf(float f) {
  union { float f; uint32_t u; } v; v.f = f;
  uint32_t u = v.u;
  uint32_t r = u + 0x7FFFu + ((u >> 16) & 1u);   // RNE
  return (short)(r >> 16);
}

// ---- kernel 1: h (f32) -> h_bf16 in workspace ----
__global__ void conv_h_bf16(const float* __restrict__ h, ushort* __restrict__ hb, int n4) {
  int i = blockIdx.x * blockDim.x + threadIdx.x;
  if (i >= n4) return;
  const float4 v = reinterpret_cast<const float4*>(h)[i];
  ushort4 o;
  o.x = (ushort)f2bf(v.x); o.y = (ushort)f2bf(v.y);
  o.z = (ushort)f2bf(v.z); o.w = (ushort)f2bf(v.w);
  reinterpret_cast<ushort4*>(hb)[i] = o;
}

// ---- kernel 2: fused gather + GEMM(M=E,K=256,N=128) + relu + dot + bias ----
// block = 256 threads = 4 waves; tile = 64 edges; wave w owns N-cols [32w,32w+32)
__global__ __launch_bounds__(256) void edge_mlp(
    const ushort* __restrict__ hb,   // [N_nodes][128] bf16
    const int*    __restrict__ src,
    const int*    __restrict__ dst,
    const float*  __restrict__ W1,   // [128][256]
    const float*  __restrict__ b1,   // [128]
    const float*  __restrict__ w2,   // [128]
    const float*  __restrict__ b2p,  // [1]
    float*        __restrict__ out,  // [E]
    int E, int ntiles)
{
  __shared__ int4  As4[2048];      // 64 rows * 512B (swizzled), 32 KiB
  __shared__ float score_w[256];   // 4 waves * 64 rows

  const int t   = threadIdx.x;
  const int w   = t >> 6;
  const int l   = t & 63;
  const int l15 = l & 15;
  const int lg  = l >> 4;          // 0..3

  // ---- preload B fragments (W1^T) into registers, bf16 ----
  bf16x8 bfrag[2][8];
  float  b1r[2], w2r[2];
#pragma unroll
  for (int nt = 0; nt < 2; ++nt) {
    const int j = w * 32 + nt * 16 + l15;       // output column (hid index)
    b1r[nt] = b1[j];
    w2r[nt] = w2[j];
#pragma unroll
    for (int kk = 0; kk < 8; ++kk) {
      const int k0 = kk * 32 + lg * 8;
      const float4* p = reinterpret_cast<const float4*>(W1 + (size_t)j * 256 + k0);
      const float4 fa = p[0], fb = p[1];
      bf16x8 b;
      b[0]=f2bf(fa.x); b[1]=f2bf(fa.y); b[2]=f2bf(fa.z); b[3]=f2bf(fa.w);
      b[4]=f2bf(fb.x); b[5]=f2bf(fb.y); b[6]=f2bf(fb.z); b[7]=f2bf(fb.w);
      bfrag[nt][kk] = b;
    }
  }
  const float b2 = b2p[0];

  const int4* hb4 = reinterpret_cast<const int4*>(hb);

  for (int tile = blockIdx.x; tile < ntiles; tile += gridDim.x) {
    const int gb = tile * 64;

    __syncthreads();   // prev iter: LDS reads done, safe to overwrite

    // ---- gather 64 edges * 512B into swizzled LDS A-tile ----
    // lane mapping: edge e = w*16 + l15 (wave covers 16 edges), part p = lg (128B each)
    {
      const int e  = w * 16 + l15;
      const int ge = gb + e;
      const int gs = (ge < E) ? ge : 0;
      const int rowid = (lg < 2) ? src[gs] : dst[gs];
      const int4* rp = hb4 + (size_t)rowid * 16 + (lg & 1) * 8;
      const int lbase = e * 32 + lg * 8;
      const int e7 = e & 7;
#pragma unroll
      for (int c = 0; c < 8; ++c) {
        As4[lbase + (c ^ e7)] = rp[c];   // chunk-idx XOR row&7 swizzle
      }
    }
    __syncthreads();

    // ---- K-loop: 8 x (4 ds_read_b128 + 8 MFMA) per wave ----
    f32x4 acc[4][2];
#pragma unroll
    for (int m = 0; m < 4; ++m)
#pragma unroll
      for (int nt = 0; nt < 2; ++nt)
        acc[m][nt] = (f32x4){0.f, 0.f, 0.f, 0.f};

#pragma unroll
    for (int kk = 0; kk < 8; ++kk) {
#pragma unroll
      for (int m = 0; m < 4; ++m) {
        const int row = m * 16 + l15;                       // A row (edge)
        const int idx = row * 32 + ((kk * 4 + lg) ^ (row & 7));
        int4 av = As4[idx];
        bf16x8 a = *reinterpret_cast<bf16x8*>(&av);
#pragma unroll
        for (int nt = 0; nt < 2; ++nt)
          acc[m][nt] = __builtin_amdgcn_mfma_f32_16x16x32_bf16(a, bfrag[nt][kk], acc[m][nt], 0, 0, 0);
      }
    }

    // ---- fused epilogue: +b1, relu, *w2, reduce over 128 cols ----
    // C/D layout: col = l&15, row(within 16) = lg*4 + r
#pragma unroll
    for (int m = 0; m < 4; ++m) {
#pragma unroll
      for (int r = 0; r < 4; ++r) {
        float v0 = acc[m][0][r] + b1r[0]; v0 = v0 > 0.f ? v0 : 0.f;
        float v1 = acc[m][1][r] + b1r[1]; v1 = v1 > 0.f ? v1 : 0.f;
        float val = v0 * w2r[0] + v1 * w2r[1];
        val += __shfl_xor(val, 1);
        val += __shfl_xor(val, 2);
        val += __shfl_xor(val, 4);
        val += __shfl_xor(val, 8);
        if (l15 == 0) score_w[w * 64 + m * 16 + lg * 4 + r] = val;
      }
    }
    __syncthreads();

    if (t < 64) {
      const int ge = gb + t;
      if (ge < E)
        out[ge] = score_w[t] + score_w[64 + t] + score_w[128 + t] + score_w[192 + t] + b2;
    }
  }
}

extern "C" void kernel_launch(void* const* d_in, const int* in_sizes, int n_in,
                              void* d_out, int out_size, void* d_ws, size_t ws_size,
                              hipStream_t stream) {
  const float* h   = (const float*)d_in[0];
  const int*   src = (const int*)d_in[1];
  const int*   dst = (const int*)d_in[2];
  const float* W1  = (const float*)d_in[3];
  const float* b1  = (const float*)d_in[4];
  const float* w2  = (const float*)d_in[5];
  const float* b2  = (const float*)d_in[6];
  float* out = (float*)d_out;

  const int nh = in_sizes[0];          // N_nodes * 128
  const int E  = in_sizes[1];

  ushort* hb = (ushort*)d_ws;          // bf16 copy of h: nh * 2 bytes

  const int n4 = nh / 4;
  hipLaunchKernelGGL(conv_h_bf16, dim3((n4 + 255) / 256), dim3(256), 0, stream, h, hb, n4);

  const int ntiles = (E + 63) / 64;
  const int grid = ntiles < 768 ? ntiles : 768;
  hipLaunchKernelGGL(edge_mlp, dim3(grid), dim3(256), 0, stream,
                     hb, src, dst, W1, b1, w2, b2, out, E, ntiles);
}

// Round 2
// 115.419 us; speedup vs baseline: 1.3318x; 1.3318x over previous
//
#include <hip/hip_runtime.h>
#include <hip/hip_bf16.h>
#include <stdint.h>

typedef short bf16x8 __attribute__((ext_vector_type(8)));
typedef float f32x4  __attribute__((ext_vector_type(4)));

__device__ __forceinline__ ushort f2bf(float f) {
  union { float f; uint32_t u; } v; v.f = f;
  uint32_t u = v.u;
  uint32_t r = u + 0x7FFFu + ((u >> 16) & 1u);   // RNE
  return (ushort)(r >> 16);
}
__device__ __forceinline__ float bf2f(ushort b) {
  union { uint32_t u; float f; } v; v.u = ((uint32_t)b) << 16;
  return v.f;
}

// ---------------- Phase 1: u = h @ A^T, v = h @ B^T  (A=W1[:, :128], B=W1[:,128:]) ----------------
// One-shot grid: block = 256 thr = 4 waves, tile = 64 nodes x 256 out-cols.
// Wave w owns out-cols [64w, 64w+64): w<2 -> u, w>=2 -> v.
__global__ __launch_bounds__(256) void node_gemm(
    const float* __restrict__ h,     // [Nn][128] f32
    const float* __restrict__ W1,    // [128][256] f32
    ushort* __restrict__ u,          // [Nn][128] bf16
    ushort* __restrict__ v,          // [Nn][128] bf16
    int Nn)
{
  __shared__ ushort As[64 * 128];    // A tile, chunk-swizzled, 16 KiB
  __shared__ ushort UV[64 * 256];    // output tile, chunk-swizzled, 32 KiB

  const int t   = threadIdx.x;
  const int w   = t >> 6;
  const int l   = t & 63;
  const int l15 = l & 15;
  const int lg  = l >> 4;
  const int n0  = blockIdx.x * 64;

  // ---- B fragments from W1 (bf16), registers ----
  bf16x8 bfrag[4][4];                // [nt][kk]
  {
#pragma unroll
    for (int nt = 0; nt < 4; ++nt) {
      const int cc   = w * 64 + nt * 16 + l15;   // global out-col 0..255
      const int jj   = cc & 127;                 // hid index
      const int koff = (cc >> 7) * 128;          // 0 for u-cols, 128 for v-cols
#pragma unroll
      for (int kk = 0; kk < 4; ++kk) {
        const float* p = W1 + (size_t)jj * 256 + koff + kk * 32 + lg * 8;
        const float4 fa = *(const float4*)p;
        const float4 fb = *(const float4*)(p + 4);
        bf16x8 b;
        b[0]=f2bf(fa.x); b[1]=f2bf(fa.y); b[2]=f2bf(fa.z); b[3]=f2bf(fa.w);
        b[4]=f2bf(fb.x); b[5]=f2bf(fb.y); b[6]=f2bf(fb.z); b[7]=f2bf(fb.w);
        bfrag[nt][kk] = b;
      }
    }
  }

  // ---- stage h tile -> bf16 LDS, swizzled in 16B chunks: chunk' = chunk ^ (row&7) ----
  {
    const float4* hb = (const float4*)h;
#pragma unroll
    for (int i = 0; i < 8; ++i) {
      const int uidx = i * 256 + t;        // float4 unit within 64x128 tile (2048 units)
      const int row  = uidx >> 5;          // 32 float4 per row
      const int f4   = uidx & 31;
      const int gn   = n0 + row;
      float4 val = make_float4(0.f, 0.f, 0.f, 0.f);
      if (gn < Nn) val = hb[(size_t)gn * 32 + f4];
      ushort4 o;
      o.x = f2bf(val.x); o.y = f2bf(val.y); o.z = f2bf(val.z); o.w = f2bf(val.w);
      const int chunk = f4 >> 1, half = f4 & 1;
      ((ushort4*)As)[row * 32 + ((chunk ^ (row & 7)) << 1) + half] = o;
    }
  }
  __syncthreads();

  // ---- MFMA: 64 per wave ----
  f32x4 acc[4][4];
#pragma unroll
  for (int m = 0; m < 4; ++m)
#pragma unroll
    for (int nt = 0; nt < 4; ++nt)
      acc[m][nt] = (f32x4){0.f, 0.f, 0.f, 0.f};

#pragma unroll
  for (int kk = 0; kk < 4; ++kk) {
#pragma unroll
    for (int m = 0; m < 4; ++m) {
      const int row   = m * 16 + l15;
      const int chunk = kk * 4 + lg;
      int4 av = ((const int4*)As)[row * 16 + (chunk ^ (row & 7))];
      bf16x8 a = *reinterpret_cast<bf16x8*>(&av);
#pragma unroll
      for (int nt = 0; nt < 4; ++nt)
        acc[m][nt] = __builtin_amdgcn_mfma_f32_16x16x32_bf16(a, bfrag[nt][kk], acc[m][nt], 0, 0, 0);
    }
  }

  // ---- transpose via LDS (swizzled), then coalesced bf16 stores ----
  // C/D layout: col = l&15, row(within 16) = lg*4 + r
#pragma unroll
  for (int m = 0; m < 4; ++m) {
#pragma unroll
    for (int nt = 0; nt < 4; ++nt) {
      const int cc    = w * 64 + nt * 16 + l15;
      const int chunk = cc >> 3, ci = cc & 7;
#pragma unroll
      for (int r = 0; r < 4; ++r) {
        const int row = m * 16 + lg * 4 + r;
        UV[row * 256 + ((chunk ^ (row & 7)) << 3) + ci] = f2bf(acc[m][nt][r]);
      }
    }
  }
  __syncthreads();

#pragma unroll
  for (int i = 0; i < 8; ++i) {
    const int uidx = i * 256 + t;          // 16B unit within 64x512B tile (2048 units)
    const int row  = uidx >> 5;            // 32 units per row
    const int cu   = uidx & 31;            // logical chunk
    const int gn   = n0 + row;
    if (gn < Nn) {
      int4 val = ((const int4*)UV)[row * 32 + (cu ^ (row & 7))];
      if (cu < 16) ((int4*)u)[(size_t)gn * 16 + cu]        = val;
      else         ((int4*)v)[(size_t)gn * 16 + (cu - 16)] = val;
    }
  }
}

// ---------------- Phase 2: score[e] = w2 . relu(u[src] + v[dst] + b1) + b2 ----------------
// Quarter-wave (16 lanes) per edge; 8 edges per wave-iteration (2 per quarter); grid-stride.
__global__ __launch_bounds__(256) void edge_score(
    const ushort* __restrict__ u, const ushort* __restrict__ v,
    const int* __restrict__ src, const int* __restrict__ dst,
    const float* __restrict__ b1, const float* __restrict__ w2,
    const float* __restrict__ b2p,
    float* __restrict__ out, int E)
{
  const int t  = threadIdx.x;
  const int l  = t & 63;
  const int q  = l & 15;     // lane within quarter
  const int lg = l >> 4;     // quarter id

  float b1r[8], w2r[8];
#pragma unroll
  for (int j = 0; j < 8; ++j) { b1r[j] = b1[q * 8 + j]; w2r[j] = w2[q * 8 + j]; }
  const float b2 = b2p[0];

  const int gw = blockIdx.x * 4 + (t >> 6);   // global wave id
  const int TW = gridDim.x * 4;
  const int4* u4 = (const int4*)u;
  const int4* v4 = (const int4*)v;

  for (int base = gw * 8; base < E; base += TW * 8) {
    const int eA = base + lg;          // edges [base, base+4)
    const int eB = base + 4 + lg;      // edges [base+4, base+8)
    const bool vA = eA < E, vB = eB < E;
    const int sA = src[vA ? eA : 0], dA = dst[vA ? eA : 0];
    const int sB = src[vB ? eB : 0], dB = dst[vB ? eB : 0];

    const int4 uA = u4[(size_t)sA * 16 + q];
    const int4 vvA = v4[(size_t)dA * 16 + q];
    const int4 uB = u4[(size_t)sB * 16 + q];
    const int4 vvB = v4[(size_t)dB * 16 + q];

    const ushort* ua = (const ushort*)&uA;
    const ushort* va = (const ushort*)&vvA;
    const ushort* ub = (const ushort*)&uB;
    const ushort* vb = (const ushort*)&vvB;

    float accA = 0.f, accB = 0.f;
#pragma unroll
    for (int j = 0; j < 8; ++j) {
      float xA = bf2f(ua[j]) + bf2f(va[j]) + b1r[j];
      xA = xA > 0.f ? xA : 0.f;
      accA = fmaf(xA, w2r[j], accA);
      float xB = bf2f(ub[j]) + bf2f(vb[j]) + b1r[j];
      xB = xB > 0.f ? xB : 0.f;
      accB = fmaf(xB, w2r[j], accB);
    }
#pragma unroll
    for (int s = 1; s < 16; s <<= 1) {
      accA += __shfl_xor(accA, s);
      accB += __shfl_xor(accB, s);
    }
    if (q == 0) {
      if (vA) out[eA] = accA + b2;
      if (vB) out[eB] = accB + b2;
    }
  }
}

extern "C" void kernel_launch(void* const* d_in, const int* in_sizes, int n_in,
                              void* d_out, int out_size, void* d_ws, size_t ws_size,
                              hipStream_t stream) {
  const float* h   = (const float*)d_in[0];
  const int*   src = (const int*)d_in[1];
  const int*   dst = (const int*)d_in[2];
  const float* W1  = (const float*)d_in[3];
  const float* b1  = (const float*)d_in[4];
  const float* w2  = (const float*)d_in[5];
  const float* b2  = (const float*)d_in[6];
  float* out = (float*)d_out;

  const int nh = in_sizes[0];          // Nn * 128
  const int Nn = nh / 128;
  const int E  = in_sizes[1];

  ushort* u = (ushort*)d_ws;                       // [Nn][128] bf16
  ushort* v = u + (size_t)Nn * 128;                // [Nn][128] bf16

  const int nb1 = (Nn + 63) / 64;
  hipLaunchKernelGGL(node_gemm, dim3(nb1), dim3(256), 0, stream, h, W1, u, v, Nn);

  hipLaunchKernelGGL(edge_score, dim3(2048), dim3(256), 0, stream,
                     u, v, src, dst, b1, w2, b2, out, E);
}

// Round 3
// 82.670 us; speedup vs baseline: 1.8593x; 1.3961x over previous
//
#include <hip/hip_runtime.h>
#include <hip/hip_bf16.h>
#include <stdint.h>

typedef short bf16x8 __attribute__((ext_vector_type(8)));
typedef float f32x4  __attribute__((ext_vector_type(4)));

__device__ __forceinline__ ushort f2b(float f) {
  __hip_bfloat16 t = __float2bfloat16(f);           // RNE; compiler can fuse to cvt_pk
  return *reinterpret_cast<ushort*>(&t);
}
__device__ __forceinline__ float bf2f(ushort b) {
  union { uint32_t u; float f; } v; v.u = ((uint32_t)b) << 16;
  return v.f;
}
__device__ __forceinline__ uint32_t pk2(float lo, float hi) {
  return (uint32_t)f2b(lo) | ((uint32_t)f2b(hi) << 16);
}
__device__ __forceinline__ bf16x8 pack8(float4 a, float4 b) {
  bf16x8 r;
  r[0]=(short)f2b(a.x); r[1]=(short)f2b(a.y); r[2]=(short)f2b(a.z); r[3]=(short)f2b(a.w);
  r[4]=(short)f2b(b.x); r[5]=(short)f2b(b.y); r[6]=(short)f2b(b.z); r[7]=(short)f2b(b.w);
  return r;
}

// ---------------- Phase 1: u = h @ A^T, v = h @ B^T (A=W1[:,:128], B=W1[:,128:]) ----------------
// Wave-independent, no LDS, no barriers. Each wave: 16-node tile x 128 cols (u OR v half).
// Output layout per node (128 ushorts): pos p = l15*8 + nt  <->  hid col = nt*16 + l15.
__global__ __launch_bounds__(256, 2) void node_uv(
    const float* __restrict__ h,     // [Nn][128] f32
    const float* __restrict__ W1,    // [128][256] f32
    ushort* __restrict__ u,          // [Nn][128] bf16 (permuted)
    ushort* __restrict__ v,          // [Nn][128] bf16 (permuted)
    int Nn, int tilesPerHalf, int npairs)
{
  const int wave = blockIdx.x * 4 + (threadIdx.x >> 6);
  const int l    = threadIdx.x & 63;
  const int l15  = l & 15;
  const int lg   = l >> 4;
  const int half  = wave & 1;         // 0 -> u, 1 -> v
  const int wpair = wave >> 1;

  // ---- B fragments for this half: bfrag[nt][kk], nt=0..7 (128 cols), kk=0..3 (K=128) ----
  bf16x8 bfrag[8][4];
#pragma unroll
  for (int nt = 0; nt < 8; ++nt) {
    const int jj = nt * 16 + l15;
    const float* wp = W1 + (size_t)jj * 256 + half * 128 + lg * 8;
#pragma unroll
    for (int kk = 0; kk < 4; ++kk) {
      const float4 fa = *(const float4*)(wp + kk * 32);
      const float4 fb = *(const float4*)(wp + kk * 32 + 4);
      bfrag[nt][kk] = pack8(fa, fb);
    }
  }

  ushort* __restrict__ outp = half ? v : u;

  for (int t = wpair; t < tilesPerHalf; t += npairs) {
    const int n0 = t * 16;
    const int nr = n0 + l15 < Nn ? n0 + l15 : Nn - 1;

    // ---- A fragments: 16 rows of h, f32 -> bf16 in-register ----
    const float* hp = h + (size_t)nr * 128 + lg * 8;
    bf16x8 afr[4];
#pragma unroll
    for (int kk = 0; kk < 4; ++kk) {
      const float4 fa = *(const float4*)(hp + kk * 32);
      const float4 fb = *(const float4*)(hp + kk * 32 + 4);
      afr[kk] = pack8(fa, fb);
    }

    f32x4 acc[8];
#pragma unroll
    for (int nt = 0; nt < 8; ++nt) acc[nt] = (f32x4){0.f, 0.f, 0.f, 0.f};

#pragma unroll
    for (int kk = 0; kk < 4; ++kk)
#pragma unroll
      for (int nt = 0; nt < 8; ++nt)
        acc[nt] = __builtin_amdgcn_mfma_f32_16x16x32_bf16(afr[kk], bfrag[nt][kk], acc[nt], 0, 0, 0);

    // ---- direct permuted stores: 16B/lane, 256B contiguous per node ----
    // C/D: row = lg*4 + r, col = nt*16 + l15; store pos = l15*8 + nt
#pragma unroll
    for (int r = 0; r < 4; ++r) {
      const int node = n0 + lg * 4 + r;
      if (node < Nn) {
        int4 st;
        st.x = (int)pk2(acc[0][r], acc[1][r]);
        st.y = (int)pk2(acc[2][r], acc[3][r]);
        st.z = (int)pk2(acc[4][r], acc[5][r]);
        st.w = (int)pk2(acc[6][r], acc[7][r]);
        *(int4*)(outp + (size_t)node * 128 + l15 * 8) = st;
      }
    }
  }
}

// ---------------- Phase 2: score[e] = w2 . relu(u[src] + v[dst] + b1) + b2 ----------------
// Quarter-wave (16 lanes) per edge, 4 edges per quarter per iteration (16 per wave).
// u/v are in permuted layout: element j of lane q's 16B chunk = hid col j*16 + q.
__global__ __launch_bounds__(256) void edge_score(
    const ushort* __restrict__ u, const ushort* __restrict__ v,
    const int* __restrict__ src, const int* __restrict__ dst,
    const float* __restrict__ b1, const float* __restrict__ w2,
    const float* __restrict__ b2p,
    float* __restrict__ out, int E)
{
  const int t  = threadIdx.x;
  const int l  = t & 63;
  const int q  = l & 15;
  const int lg = l >> 4;

  float b1r[8], w2r[8];
#pragma unroll
  for (int j = 0; j < 8; ++j) { b1r[j] = b1[j * 16 + q]; w2r[j] = w2[j * 16 + q]; }
  const float b2 = b2p[0];

  const int gw = blockIdx.x * 4 + (t >> 6);
  const int TW = gridDim.x * 4;
  const int4* u4 = (const int4*)u;
  const int4* v4 = (const int4*)v;

  for (int base = gw * 16; base < E; base += TW * 16) {
    int   e[4]; bool ok[4]; int4 ug[4], vg[4];
#pragma unroll
    for (int i = 0; i < 4; ++i) {
      e[i]  = base + i * 4 + lg;
      ok[i] = e[i] < E;
      const int s = src[ok[i] ? e[i] : 0];
      const int d = dst[ok[i] ? e[i] : 0];
      ug[i] = u4[(size_t)s * 16 + q];
      vg[i] = v4[(size_t)d * 16 + q];
    }
#pragma unroll
    for (int i = 0; i < 4; ++i) {
      const ushort* ua = (const ushort*)&ug[i];
      const ushort* va = (const ushort*)&vg[i];
      float acc = 0.f;
#pragma unroll
      for (int j = 0; j < 8; ++j) {
        float x = bf2f(ua[j]) + bf2f(va[j]) + b1r[j];
        x = x > 0.f ? x : 0.f;
        acc = fmaf(x, w2r[j], acc);
      }
      acc += __shfl_xor(acc, 1);
      acc += __shfl_xor(acc, 2);
      acc += __shfl_xor(acc, 4);
      acc += __shfl_xor(acc, 8);
      if (q == 0 && ok[i]) out[e[i]] = acc + b2;
    }
  }
}

extern "C" void kernel_launch(void* const* d_in, const int* in_sizes, int n_in,
                              void* d_out, int out_size, void* d_ws, size_t ws_size,
                              hipStream_t stream) {
  const float* h   = (const float*)d_in[0];
  const int*   src = (const int*)d_in[1];
  const int*   dst = (const int*)d_in[2];
  const float* W1  = (const float*)d_in[3];
  const float* b1  = (const float*)d_in[4];
  const float* w2  = (const float*)d_in[5];
  const float* b2  = (const float*)d_in[6];
  float* out = (float*)d_out;

  const int nh = in_sizes[0];          // Nn * 128
  const int Nn = nh / 128;
  const int E  = in_sizes[1];

  ushort* u = (ushort*)d_ws;                       // [Nn][128] bf16 (permuted)
  ushort* v = u + (size_t)Nn * 128;

  const int tilesPerHalf = (Nn + 15) / 16;
  const int nblocks1 = 512;                        // 2048 waves -> 1024 pairs
  const int npairs   = nblocks1 * 4 / 2;
  hipLaunchKernelGGL(node_uv, dim3(nblocks1), dim3(256), 0, stream,
                     h, W1, u, v, Nn, tilesPerHalf, npairs);

  hipLaunchKernelGGL(edge_score, dim3(2048), dim3(256), 0, stream,
                     u, v, src, dst, b1, w2, b2, out, E);
}

// Round 4
// 63.939 us; speedup vs baseline: 2.4040x; 1.2930x over previous
//
#include <hip/hip_runtime.h>
#include <hip/hip_bf16.h>
#include <stdint.h>

typedef short bf16x8 __attribute__((ext_vector_type(8)));
typedef float f32x4  __attribute__((ext_vector_type(4)));

__device__ __forceinline__ ushort f2b(float f) {
  __hip_bfloat16 t = __float2bfloat16(f);
  return *reinterpret_cast<ushort*>(&t);
}
__device__ __forceinline__ bf16x8 pack8(float4 a, float4 b) {
  bf16x8 r;
  r[0]=(short)f2b(a.x); r[1]=(short)f2b(a.y); r[2]=(short)f2b(a.z); r[3]=(short)f2b(a.w);
  r[4]=(short)f2b(b.x); r[5]=(short)f2b(b.y); r[6]=(short)f2b(b.z); r[7]=(short)f2b(b.w);
  return r;
}

// ---------------- Phase 0: repack W1 -> bf16 B-fragment blob (coalesced preload later) ----------
// blob[ ((half*8+nt)*4+kk)*64 + lane ] = 16B frag for (half,nt,kk,lane), lane=(lg*16+l15)
// frag elems = W1[nt*16+l15][half*128 + kk*32 + lg*8 + 0..7]
__global__ void repack_W1(const float* __restrict__ W1, int4* __restrict__ blob) {
  const int tid = blockIdx.x * 256 + threadIdx.x;     // 0..4095
  const int l15  = tid & 15;
  const int lg   = (tid >> 4) & 3;
  const int kk   = (tid >> 6) & 3;
  const int nt   = (tid >> 8) & 7;
  const int half = (tid >> 11) & 1;
  const float* wp = W1 + (size_t)(nt * 16 + l15) * 256 + half * 128 + kk * 32 + lg * 8;
  const float4 fa = *(const float4*)wp;
  const float4 fb = *(const float4*)(wp + 4);
  bf16x8 r = pack8(fa, fb);
  blob[tid] = *reinterpret_cast<int4*>(&r);
}

// ---------------- Phase 1: u/v = h @ A^T / h @ B^T -> int8 + per-node scale ----------------
// Block = 256 thr = 4 waves = 2 pairs. Pair = {u-half wave, v-half wave}, sharing one staged
// h tile (16 nodes x 512B f32) in LDS (read h ONCE). XOR-swizzled 16B chunks: slot = c^(row&7).
// Output (per node, 128 int8): byte pos l15*8 + nt  <->  hid col nt*16 + l15. b1 folded into u.
__global__ __launch_bounds__(256, 2) void node_uv(
    const float* __restrict__ h, const int4* __restrict__ blob,
    const float* __restrict__ b1,
    uint8_t* __restrict__ u8, uint8_t* __restrict__ v8,
    float* __restrict__ su, float* __restrict__ sv,
    int Nn, int NT, int npairs, int niter)
{
  __shared__ float4 As[2][512];          // [pair][row*32 + slot], 8 KiB each

  const int t0   = threadIdx.x;
  const int w    = t0 >> 6;
  const int l    = t0 & 63;
  const int l15  = l & 15;
  const int lg   = l >> 4;
  const int pair = w >> 1;
  const int half = w & 1;                // 0 -> u, 1 -> v
  const int gp   = blockIdx.x * 2 + pair;

  // coalesced B-fragment preload from blob
  bf16x8 bfrag[8][4];
#pragma unroll
  for (int nt = 0; nt < 8; ++nt)
#pragma unroll
    for (int kk = 0; kk < 4; ++kk) {
      int4 x = blob[((half * 8 + nt) * 4 + kk) * 64 + l];
      bfrag[nt][kk] = *reinterpret_cast<bf16x8*>(&x);
    }

  float b1r[8];
#pragma unroll
  for (int nt = 0; nt < 8; ++nt) b1r[nt] = half ? 0.f : b1[nt * 16 + l15];

  uint8_t* __restrict__ outp = half ? v8 : u8;
  float*   __restrict__ outs = half ? sv : su;

  float4* Ap = As[pair];
  const int pl = half * 64 + l;          // pair-local thread 0..127
  const float4* h4 = (const float4*)h;

  int t = gp;
  // prologue: stage tile t
  if (t < NT) {
    const size_t hbase = (size_t)t * 16 * 32;
#pragma unroll
    for (int k = 0; k < 4; ++k) {
      const int i = k * 128 + pl;        // unit: row=i>>5, chunk c=i&31
      const int row = i >> 5, c = i & 31;
      const int gr = t * 16 + row;
      float4 g = h4[gr < Nn ? hbase + i : 0];
      Ap[row * 32 + (c ^ (row & 7))] = g;
    }
  }
  __syncthreads();

  for (int it = 0; it < niter; ++it) {
    const int tn = t + npairs;

    // T14: issue next-tile loads early
    float4 g[4];
    if (tn < NT) {
      const size_t hbase = (size_t)tn * 16 * 32;
#pragma unroll
      for (int k = 0; k < 4; ++k) {
        const int i = k * 128 + pl;
        const int gr = tn * 16 + (i >> 5);
        g[k] = h4[gr < Nn ? hbase + i : 0];
      }
    }

    if (t < NT) {
      // ---- fragments from LDS + MFMA ----
      f32x4 acc[8];
#pragma unroll
      for (int nt = 0; nt < 8; ++nt) acc[nt] = (f32x4){0.f, 0.f, 0.f, 0.f};

#pragma unroll
      for (int kk = 0; kk < 4; ++kk) {
        const int c0 = lg * 2 + kk * 8;
        const float4 fa = Ap[l15 * 32 + ((c0    ) ^ (l15 & 7))];
        const float4 fb = Ap[l15 * 32 + ((c0 + 1) ^ (l15 & 7))];
        const bf16x8 a = pack8(fa, fb);
#pragma unroll
        for (int nt = 0; nt < 8; ++nt)
          acc[nt] = __builtin_amdgcn_mfma_f32_16x16x32_bf16(a, bfrag[nt][kk], acc[nt], 0, 0, 0);
      }

      // ---- int8 quantize per node ----
      const int n0 = t * 16;
#pragma unroll
      for (int r = 0; r < 4; ++r) {
        float vals[8];
        float m = 1e-30f;
#pragma unroll
        for (int nt = 0; nt < 8; ++nt) {
          const float x = acc[nt][r] + b1r[nt];
          vals[nt] = x;
          m = fmaxf(m, fabsf(x));
        }
        m = fmaxf(m, __shfl_xor(m, 1));
        m = fmaxf(m, __shfl_xor(m, 2));
        m = fmaxf(m, __shfl_xor(m, 4));
        m = fmaxf(m, __shfl_xor(m, 8));
        const float inv = 127.0f * __builtin_amdgcn_rcpf(m);
        uint32_t lo = 0, hi = 0;
#pragma unroll
        for (int j = 0; j < 4; ++j) {
          const int q = (int)rintf(vals[j] * inv);
          lo |= (uint32_t)(q & 255) << (8 * j);
        }
#pragma unroll
        for (int j = 0; j < 4; ++j) {
          const int q = (int)rintf(vals[4 + j] * inv);
          hi |= (uint32_t)(q & 255) << (8 * j);
        }
        const int node = n0 + lg * 4 + r;
        if (node < Nn) {
          *(uint2*)(outp + (size_t)node * 128 + l15 * 8) = make_uint2(lo, hi);
          if (l15 == 0) outs[node] = m * (1.0f / 127.0f);
        }
      }
    }

    __syncthreads();                      // all reads of Ap done
    if (tn < NT) {
#pragma unroll
      for (int k = 0; k < 4; ++k) {
        const int i = k * 128 + pl;
        const int row = i >> 5, c = i & 31;
        Ap[row * 32 + (c ^ (row & 7))] = g[k];
      }
    }
    __syncthreads();                      // writes visible
    t = tn;
  }
}

// ---------------- Phase 2: score[e] = w2 . relu(su[s]*u8[s] + sv[d]*v8[d]) + b2 ----------------
// 16-lane group per edge, 4 edges per group-iteration. Lane q reads 8 int8 = cols {j*16+q}.
__global__ __launch_bounds__(256) void edge_score_i8(
    const uint8_t* __restrict__ u8, const uint8_t* __restrict__ v8,
    const float* __restrict__ su, const float* __restrict__ sv,
    const int* __restrict__ src, const int* __restrict__ dst,
    const float* __restrict__ w2, const float* __restrict__ b2p,
    float* __restrict__ out, int E)
{
  const int t  = threadIdx.x;
  const int l  = t & 63;
  const int q  = l & 15;
  const int lg = l >> 4;

  float w2r[8];
#pragma unroll
  for (int j = 0; j < 8; ++j) w2r[j] = w2[j * 16 + q];
  const float b2 = b2p[0];

  const int gw = blockIdx.x * 4 + (t >> 6);
  const int TW = gridDim.x * 4;

  for (int base = gw * 16; base < E; base += TW * 16) {
    int e[4]; bool ok[4];
    uint2 ug[4], vg[4];
    float ss[4], sd[4];
#pragma unroll
    for (int i = 0; i < 4; ++i) {
      e[i]  = base + i * 4 + lg;
      ok[i] = e[i] < E;
      const int eS = ok[i] ? e[i] : 0;
      const int s = src[eS];
      const int d = dst[eS];
      ug[i] = *(const uint2*)(u8 + (size_t)s * 128 + q * 8);
      vg[i] = *(const uint2*)(v8 + (size_t)d * 128 + q * 8);
      ss[i] = su[s];
      sd[i] = sv[d];
    }
#pragma unroll
    for (int i = 0; i < 4; ++i) {
      const int ux = (int)ug[i].x, uy = (int)ug[i].y;
      const int vx = (int)vg[i].x, vy = (int)vg[i].y;
      float acc = 0.f;
#pragma unroll
      for (int j = 0; j < 4; ++j) {
        const float cu = (float)((ux << (24 - 8 * j)) >> 24);
        const float cv = (float)((vx << (24 - 8 * j)) >> 24);
        float x = cu * ss[i] + cv * sd[i];
        x = fmaxf(x, 0.f);
        acc = fmaf(x, w2r[j], acc);
      }
#pragma unroll
      for (int j = 0; j < 4; ++j) {
        const float cu = (float)((uy << (24 - 8 * j)) >> 24);
        const float cv = (float)((vy << (24 - 8 * j)) >> 24);
        float x = cu * ss[i] + cv * sd[i];
        x = fmaxf(x, 0.f);
        acc = fmaf(x, w2r[4 + j], acc);
      }
      acc += __shfl_xor(acc, 1);
      acc += __shfl_xor(acc, 2);
      acc += __shfl_xor(acc, 4);
      acc += __shfl_xor(acc, 8);
      if (q == 0 && ok[i]) out[e[i]] = acc + b2;
    }
  }
}

extern "C" void kernel_launch(void* const* d_in, const int* in_sizes, int n_in,
                              void* d_out, int out_size, void* d_ws, size_t ws_size,
                              hipStream_t stream) {
  const float* h   = (const float*)d_in[0];
  const int*   src = (const int*)d_in[1];
  const int*   dst = (const int*)d_in[2];
  const float* W1  = (const float*)d_in[3];
  const float* b1  = (const float*)d_in[4];
  const float* w2  = (const float*)d_in[5];
  const float* b2  = (const float*)d_in[6];
  float* out = (float*)d_out;

  const int nh = in_sizes[0];
  const int Nn = nh / 128;
  const int E  = in_sizes[1];

  uint8_t* ws = (uint8_t*)d_ws;
  int4*  blob = (int4*)ws;                                          // 64 KiB
  size_t off  = 65536;
  float* su   = (float*)(ws + off);  off += (size_t)Nn * 4;
  off = (off + 511) & ~(size_t)511;
  float* sv   = (float*)(ws + off);  off += (size_t)Nn * 4;
  off = (off + 511) & ~(size_t)511;
  uint8_t* u8 = ws + off;            off += (size_t)Nn * 128;
  uint8_t* v8 = ws + off;

  hipLaunchKernelGGL(repack_W1, dim3(16), dim3(256), 0, stream, W1, blob);

  const int NT     = (Nn + 15) / 16;
  const int nblk1  = 512;
  const int npairs = nblk1 * 2;
  const int niter  = (NT + npairs - 1) / npairs;
  hipLaunchKernelGGL(node_uv, dim3(nblk1), dim3(256), 0, stream,
                     h, blob, b1, u8, v8, su, sv, Nn, NT, npairs, niter);

  hipLaunchKernelGGL(edge_score_i8, dim3(2048), dim3(256), 0, stream,
                     u8, v8, su, sv, src, dst, w2, b2, out, E);
}

// Round 5
// 61.330 us; speedup vs baseline: 2.5063x; 1.0425x over previous
//
#include <hip/hip_runtime.h>
#include <hip/hip_bf16.h>
#include <stdint.h>

typedef short bf16x8 __attribute__((ext_vector_type(8)));
typedef float f32x4  __attribute__((ext_vector_type(4)));

__device__ __forceinline__ ushort f2b(float f) {
  __hip_bfloat16 t = __float2bfloat16(f);
  return *reinterpret_cast<ushort*>(&t);
}
__device__ __forceinline__ bf16x8 pack8(float4 a, float4 b) {
  bf16x8 r;
  r[0]=(short)f2b(a.x); r[1]=(short)f2b(a.y); r[2]=(short)f2b(a.z); r[3]=(short)f2b(a.w);
  r[4]=(short)f2b(b.x); r[5]=(short)f2b(b.y); r[6]=(short)f2b(b.z); r[7]=(short)f2b(b.w);
  return r;
}

// ---------------- Phase 0: repack W1 -> bf16 B-fragment blob ----------------
// blob[ ((half*8+nt)*4+kk)*64 + lane ] = 16B frag; frag elems =
// W1[nt*16+l15][half*128 + kk*32 + lg*8 + 0..7], lane = lg*16+l15
__global__ void repack_W1(const float* __restrict__ W1, int4* __restrict__ blob) {
  const int tid = blockIdx.x * 256 + threadIdx.x;     // 0..4095
  const int l15  = tid & 15;
  const int lg   = (tid >> 4) & 3;
  const int kk   = (tid >> 6) & 3;
  const int nt   = (tid >> 8) & 7;
  const int half = (tid >> 11) & 1;
  const float* wp = W1 + (size_t)(nt * 16 + l15) * 256 + half * 128 + kk * 32 + lg * 8;
  const float4 fa = *(const float4*)wp;
  const float4 fb = *(const float4*)(wp + 4);
  bf16x8 r = pack8(fa, fb);
  blob[tid] = *reinterpret_cast<int4*>(&r);
}

// ---------------- Phase 1: u/v = h @ A^T / h @ B^T -> biased uint8 + per-node scale ----------
// Block = 4 waves = 2 pairs; pair = {u-wave, v-wave} sharing one bf16 LDS tile (16 nodes x 256B).
// Staging converts f32->bf16 once. XOR swizzle on 16B chunks: slot = chunk ^ (row&7).
// Output (per node, 128 uint8): byte pos l15*8 + nt <-> hid col nt*16 + l15; stored value q+128.
// b1 folded into u pre-quantization.
__global__ __launch_bounds__(256, 2) void node_uv(
    const float* __restrict__ h, const int4* __restrict__ blob,
    const float* __restrict__ b1,
    uint8_t* __restrict__ u8, uint8_t* __restrict__ v8,
    float* __restrict__ su, float* __restrict__ sv,
    int Nn, int NT, int npairs, int niter)
{
  __shared__ ushort As[2][2048];         // [pair][row*128 + swizzled], 4 KiB each

  const int t0   = threadIdx.x;
  const int w    = t0 >> 6;
  const int l    = t0 & 63;
  const int l15  = l & 15;
  const int lg   = l >> 4;
  const int pair = w >> 1;
  const int half = w & 1;                // 0 -> u, 1 -> v
  const int gp   = blockIdx.x * 2 + pair;

  // coalesced B-fragment preload (L2-hot blob)
  bf16x8 bfrag[8][4];
#pragma unroll
  for (int nt = 0; nt < 8; ++nt)
#pragma unroll
    for (int kk = 0; kk < 4; ++kk) {
      int4 x = blob[((half * 8 + nt) * 4 + kk) * 64 + l];
      bfrag[nt][kk] = *reinterpret_cast<bf16x8*>(&x);
    }

  float b1r[8];
#pragma unroll
  for (int nt = 0; nt < 8; ++nt) b1r[nt] = half ? 0.f : b1[nt * 16 + l15];

  uint8_t* __restrict__ outp = half ? v8 : u8;
  float*   __restrict__ outs = half ? sv : su;

  ushort* Ap = As[pair];
  const int pl = half * 64 + l;          // pair-local thread 0..127
  const float4* h4 = (const float4*)h;

  int t = gp;
  // prologue: stage tile t (convert during stage)
  if (t < NT) {
    const size_t hb = (size_t)t * 512;
#pragma unroll
    for (int k = 0; k < 4; ++k) {
      const int i = k * 128 + pl, row = i >> 5, cc = i & 31;
      const int gr = t * 16 + row;
      float4 g = h4[gr < Nn ? hb + i : 0];
      ushort4 o; o.x = f2b(g.x); o.y = f2b(g.y); o.z = f2b(g.z); o.w = f2b(g.w);
      *(ushort4*)(Ap + row * 128 + (((cc >> 1) ^ (row & 7)) << 3) + (cc & 1) * 4) = o;
    }
  }
  __syncthreads();

  for (int it = 0; it < niter; ++it) {
    const int tn = t + npairs;

    // T14: issue next-tile loads early
    float4 g[4];
    if (tn < NT) {
      const size_t hb = (size_t)tn * 512;
#pragma unroll
      for (int k = 0; k < 4; ++k) {
        const int i = k * 128 + pl;
        const int gr = tn * 16 + (i >> 5);
        g[k] = h4[gr < Nn ? hb + i : 0];
      }
    }

    if (t < NT) {
      f32x4 acc[8];
#pragma unroll
      for (int nt = 0; nt < 8; ++nt) acc[nt] = (f32x4){0.f, 0.f, 0.f, 0.f};

#pragma unroll
      for (int kk = 0; kk < 4; ++kk) {
        const int slot = (kk * 4 + lg) ^ (l15 & 7);
        int4 av = *(const int4*)(Ap + l15 * 128 + slot * 8);
        const bf16x8 a = *reinterpret_cast<bf16x8*>(&av);
#pragma unroll
        for (int nt = 0; nt < 8; ++nt)
          acc[nt] = __builtin_amdgcn_mfma_f32_16x16x32_bf16(a, bfrag[nt][kk], acc[nt], 0, 0, 0);
      }

      // ---- biased-uint8 quantize per node ----
      const int n0 = t * 16;
#pragma unroll
      for (int r = 0; r < 4; ++r) {
        float vals[8];
        float m = 1e-30f;
#pragma unroll
        for (int nt = 0; nt < 8; ++nt) {
          const float x = acc[nt][r] + b1r[nt];
          vals[nt] = x;
          m = fmaxf(m, fabsf(x));
        }
        m = fmaxf(m, __shfl_xor(m, 1));
        m = fmaxf(m, __shfl_xor(m, 2));
        m = fmaxf(m, __shfl_xor(m, 4));
        m = fmaxf(m, __shfl_xor(m, 8));
        const float inv = 127.0f * __builtin_amdgcn_rcpf(m);
        uint32_t lo = 0, hi = 0;
#pragma unroll
        for (int j = 0; j < 4; ++j) {
          const int q = (int)rintf(vals[j] * inv) + 128;        // 1..255
          lo |= (uint32_t)q << (8 * j);
        }
#pragma unroll
        for (int j = 0; j < 4; ++j) {
          const int q = (int)rintf(vals[4 + j] * inv) + 128;
          hi |= (uint32_t)q << (8 * j);
        }
        const int node = n0 + lg * 4 + r;
        if (node < Nn) {
          *(uint2*)(outp + (size_t)node * 128 + l15 * 8) = make_uint2(lo, hi);
          if (l15 == 0) outs[node] = m * (1.0f / 127.0f);
        }
      }
    }

    __syncthreads();                      // all reads of Ap done
    if (tn < NT) {
#pragma unroll
      for (int k = 0; k < 4; ++k) {
        const int i = k * 128 + pl, row = i >> 5, cc = i & 31;
        ushort4 o; o.x = f2b(g[k].x); o.y = f2b(g[k].y); o.z = f2b(g[k].z); o.w = f2b(g[k].w);
        *(ushort4*)(Ap + row * 128 + (((cc >> 1) ^ (row & 7)) << 3) + (cc & 1) * 4) = o;
      }
    }
    __syncthreads();                      // writes visible
    t = tn;
  }
}

// ---------------- Phase 2: score[e] = w2 . relu(su[s]*(u-128) + sv[d]*(v-128)) + b2 ----------
// 16-lane group per edge, 4 edges per group-iteration. Lane q reads bytes = cols {j*16+q}.
__global__ __launch_bounds__(256) void edge_score_i8(
    const uint8_t* __restrict__ u8, const uint8_t* __restrict__ v8,
    const float* __restrict__ su, const float* __restrict__ sv,
    const int* __restrict__ src, const int* __restrict__ dst,
    const float* __restrict__ w2, const float* __restrict__ b2p,
    float* __restrict__ out, int E)
{
  const int t  = threadIdx.x;
  const int l  = t & 63;
  const int q  = l & 15;
  const int lg = l >> 4;

  float w2r[8];
#pragma unroll
  for (int j = 0; j < 8; ++j) w2r[j] = w2[j * 16 + q];
  const float b2 = b2p[0];

  const int gw = blockIdx.x * 4 + (t >> 6);
  const int TW = gridDim.x * 4;

  for (int base = gw * 16; base < E; base += TW * 16) {
    int e[4]; bool ok[4];
    uint2 ug[4], vg[4];
    float ss[4], sd[4];
#pragma unroll
    for (int i = 0; i < 4; ++i) {
      e[i]  = base + i * 4 + lg;
      ok[i] = e[i] < E;
      const int eS = ok[i] ? e[i] : 0;
      const int s = src[eS];
      const int d = dst[eS];
      ug[i] = *(const uint2*)(u8 + (size_t)s * 128 + q * 8);
      vg[i] = *(const uint2*)(v8 + (size_t)d * 128 + q * 8);
      ss[i] = su[s];
      sd[i] = sv[d];
    }
#pragma unroll
    for (int i = 0; i < 4; ++i) {
      const uint32_t ux = ug[i].x, uy = ug[i].y;
      const uint32_t vx = vg[i].x, vy = vg[i].y;
      const float bse = -128.0f * (ss[i] + sd[i]);
      float acc = 0.f;
#pragma unroll
      for (int j = 0; j < 4; ++j) {
        const float cu = (float)((ux >> (8 * j)) & 0xffu);   // v_cvt_f32_ubyteN
        const float cv = (float)((vx >> (8 * j)) & 0xffu);
        float x = fmaf(cu, ss[i], fmaf(cv, sd[i], bse));
        x = fmaxf(x, 0.f);
        acc = fmaf(x, w2r[j], acc);
      }
#pragma unroll
      for (int j = 0; j < 4; ++j) {
        const float cu = (float)((uy >> (8 * j)) & 0xffu);
        const float cv = (float)((vy >> (8 * j)) & 0xffu);
        float x = fmaf(cu, ss[i], fmaf(cv, sd[i], bse));
        x = fmaxf(x, 0.f);
        acc = fmaf(x, w2r[4 + j], acc);
      }
      acc += __shfl_xor(acc, 1);
      acc += __shfl_xor(acc, 2);
      acc += __shfl_xor(acc, 4);
      acc += __shfl_xor(acc, 8);
      if (q == 0 && ok[i]) out[e[i]] = acc + b2;
    }
  }
}

extern "C" void kernel_launch(void* const* d_in, const int* in_sizes, int n_in,
                              void* d_out, int out_size, void* d_ws, size_t ws_size,
                              hipStream_t stream) {
  const float* h   = (const float*)d_in[0];
  const int*   src = (const int*)d_in[1];
  const int*   dst = (const int*)d_in[2];
  const float* W1  = (const float*)d_in[3];
  const float* b1  = (const float*)d_in[4];
  const float* w2  = (const float*)d_in[5];
  const float* b2  = (const float*)d_in[6];
  float* out = (float*)d_out;

  const int nh = in_sizes[0];
  const int Nn = nh / 128;
  const int E  = in_sizes[1];

  uint8_t* ws = (uint8_t*)d_ws;
  int4*  blob = (int4*)ws;                                          // 64 KiB
  size_t off  = 65536;
  float* su   = (float*)(ws + off);  off += (size_t)Nn * 4;
  off = (off + 511) & ~(size_t)511;
  float* sv   = (float*)(ws + off);  off += (size_t)Nn * 4;
  off = (off + 511) & ~(size_t)511;
  uint8_t* u8 = ws + off;            off += (size_t)Nn * 128;
  uint8_t* v8 = ws + off;

  hipLaunchKernelGGL(repack_W1, dim3(16), dim3(256), 0, stream, W1, blob);

  const int NT     = (Nn + 15) / 16;
  const int nblk1  = 768;
  const int npairs = nblk1 * 2;
  const int niter  = (NT + npairs - 1) / npairs;
  hipLaunchKernelGGL(node_uv, dim3(nblk1), dim3(256), 0, stream,
                     h, blob, b1, u8, v8, su, sv, Nn, NT, npairs, niter);

  hipLaunchKernelGGL(edge_score_i8, dim3(2048), dim3(256), 0, stream,
                     u8, v8, su, sv, src, dst, w2, b2, out, E);
}

// Round 6
// 60.171 us; speedup vs baseline: 2.5546x; 1.0193x over previous
//
#include <hip/hip_runtime.h>
#include <hip/hip_bf16.h>
#include <stdint.h>

typedef short bf16x8 __attribute__((ext_vector_type(8)));
typedef float f32x4  __attribute__((ext_vector_type(4)));

__device__ __forceinline__ ushort f2b(float f) {
  __hip_bfloat16 t = __float2bfloat16(f);
  return *reinterpret_cast<ushort*>(&t);
}
__device__ __forceinline__ bf16x8 pack8(float4 a, float4 b) {
  bf16x8 r;
  r[0]=(short)f2b(a.x); r[1]=(short)f2b(a.y); r[2]=(short)f2b(a.z); r[3]=(short)f2b(a.w);
  r[4]=(short)f2b(b.x); r[5]=(short)f2b(b.y); r[6]=(short)f2b(b.z); r[7]=(short)f2b(b.w);
  return r;
}

// ---------------- Phase 0: repack W1 -> bf16 B-fragment blob ----------------
// blob[ ((half*8+nt)*4+kk)*64 + lane ] = 16B frag; frag elems =
// W1[nt*16+l15][half*128 + kk*32 + lg*8 + 0..7], lane = lg*16+l15
__global__ void repack_W1(const float* __restrict__ W1, int4* __restrict__ blob) {
  const int tid = blockIdx.x * 256 + threadIdx.x;     // 0..4095
  const int l15  = tid & 15;
  const int lg   = (tid >> 4) & 3;
  const int kk   = (tid >> 6) & 3;
  const int nt   = (tid >> 8) & 7;
  const int half = (tid >> 11) & 1;
  const float* wp = W1 + (size_t)(nt * 16 + l15) * 256 + half * 128 + kk * 32 + lg * 8;
  const float4 fa = *(const float4*)wp;
  const float4 fb = *(const float4*)(wp + 4);
  bf16x8 r = pack8(fa, fb);
  blob[tid] = *reinterpret_cast<int4*>(&r);
}

// ---------------- Phase 1: u/v = h @ A^T / h @ B^T -> biased uint8 + per-half scales --------
// Block = 4 waves sharing ONE 16-node bf16 A-tile. Wave w owns output cols [64w, 64w+64):
// half = w>>1 (0->u, 1->v), sub-half hw = w&1. bfrag = 64 VGPR -> 4 waves/SIMD occupancy.
// Scales: outs[node*2 + hw] covers that wave's 64 cols. b1 folded into u pre-quant.
// Byte layout per node (128 B): byte pos l15*8 + hw*4 + ntl <-> within-half col
// (hw*4+ntl)*16 + l15; i.e. byte j of 8B chunk q <-> col j*16 + q (j<4 scale .x, j>=4 .y).
__global__ __launch_bounds__(256, 4) void node_uv(
    const float* __restrict__ h, const int4* __restrict__ blob,
    const float* __restrict__ b1,
    uint8_t* __restrict__ u8, uint8_t* __restrict__ v8,
    float* __restrict__ su, float* __restrict__ sv,   // [Nn][2]
    int Nn, int NT, int nblocks, int niter)
{
  __shared__ ushort As[2048];            // 16 rows x 128 cols bf16, XOR-swizzled 16B chunks; 4 KiB

  const int t0   = threadIdx.x;
  const int w    = t0 >> 6;
  const int l    = t0 & 63;
  const int l15  = l & 15;
  const int lg   = l >> 4;
  const int half = w >> 1;               // 0 -> u, 1 -> v
  const int hw   = w & 1;                // which 64-col sub-half

  // coalesced B-fragment preload (L2-hot blob): wave's 64 cols
  bf16x8 bfrag[4][4];
#pragma unroll
  for (int ntl = 0; ntl < 4; ++ntl)
#pragma unroll
    for (int kk = 0; kk < 4; ++kk) {
      int4 x = blob[((half * 8 + hw * 4 + ntl) * 4 + kk) * 64 + l];
      bfrag[ntl][kk] = *reinterpret_cast<bf16x8*>(&x);
    }

  float b1r[4];
#pragma unroll
  for (int ntl = 0; ntl < 4; ++ntl)
    b1r[ntl] = half ? 0.f : b1[hw * 64 + ntl * 16 + l15];

  uint8_t* __restrict__ outp = half ? v8 : u8;
  float*   __restrict__ outs = half ? sv : su;

  const float4* h4 = (const float4*)h;

  int t = blockIdx.x;
  // prologue: stage tile t (convert f32->bf16 during stage; swizzle 16B chunks)
  if (t < NT) {
    const size_t hb = (size_t)t * 512;
#pragma unroll
    for (int k = 0; k < 2; ++k) {
      const int i = k * 256 + t0, row = i >> 5, c = i & 31;
      const int gr = t * 16 + row;
      float4 g = h4[gr < Nn ? hb + i : 0];
      ushort4 o; o.x = f2b(g.x); o.y = f2b(g.y); o.z = f2b(g.z); o.w = f2b(g.w);
      *(ushort4*)(As + row * 128 + (((c >> 1) ^ (row & 7)) << 3) + (c & 1) * 4) = o;
    }
  }
  __syncthreads();

  for (int it = 0; it < niter; ++it) {
    const int tn = t + nblocks;

    // T14: issue next-tile loads early (held in regs across compute)
    float4 g[2];
    if (tn < NT) {
      const size_t hb = (size_t)tn * 512;
#pragma unroll
      for (int k = 0; k < 2; ++k) {
        const int i = k * 256 + t0;
        const int gr = tn * 16 + (i >> 5);
        g[k] = h4[gr < Nn ? hb + i : 0];
      }
    }

    if (t < NT) {
      f32x4 acc[4];
#pragma unroll
      for (int ntl = 0; ntl < 4; ++ntl) acc[ntl] = (f32x4){0.f, 0.f, 0.f, 0.f};

#pragma unroll
      for (int kk = 0; kk < 4; ++kk) {
        const int slot = (kk * 4 + lg) ^ (l15 & 7);
        int4 av = *(const int4*)(As + l15 * 128 + slot * 8);
        const bf16x8 a = *reinterpret_cast<bf16x8*>(&av);
#pragma unroll
        for (int ntl = 0; ntl < 4; ++ntl)
          acc[ntl] = __builtin_amdgcn_mfma_f32_16x16x32_bf16(a, bfrag[ntl][kk], acc[ntl], 0, 0, 0);
      }

      // ---- biased-uint8 quantize: per node, per 64-col sub-half ----
      const int n0 = t * 16;
#pragma unroll
      for (int r = 0; r < 4; ++r) {
        float vals[4];
        float m = 1e-30f;
#pragma unroll
        for (int ntl = 0; ntl < 4; ++ntl) {
          const float x = acc[ntl][r] + b1r[ntl];
          vals[ntl] = x;
          m = fmaxf(m, fabsf(x));
        }
        m = fmaxf(m, __shfl_xor(m, 1));
        m = fmaxf(m, __shfl_xor(m, 2));
        m = fmaxf(m, __shfl_xor(m, 4));
        m = fmaxf(m, __shfl_xor(m, 8));
        const float inv = 127.0f * __builtin_amdgcn_rcpf(m);
        uint32_t pk = 0;
#pragma unroll
        for (int j = 0; j < 4; ++j) {
          const int q = (int)rintf(vals[j] * inv) + 128;        // 1..255
          pk |= (uint32_t)q << (8 * j);
        }
        const int node = n0 + lg * 4 + r;
        if (node < Nn) {
          *(uint32_t*)(outp + (size_t)node * 128 + l15 * 8 + hw * 4) = pk;
          if (l15 == 0) outs[node * 2 + hw] = m * (1.0f / 127.0f);
        }
      }
    }

    __syncthreads();                      // all reads of As done
    if (tn < NT) {
#pragma unroll
      for (int k = 0; k < 2; ++k) {
        const int i = k * 256 + t0, row = i >> 5, c = i & 31;
        ushort4 o; o.x = f2b(g[k].x); o.y = f2b(g[k].y); o.z = f2b(g[k].z); o.w = f2b(g[k].w);
        *(ushort4*)(As + row * 128 + (((c >> 1) ^ (row & 7)) << 3) + (c & 1) * 4) = o;
      }
    }
    __syncthreads();                      // writes visible
    t = tn;
  }
}

// ---------------- Phase 2: score[e] = w2 . relu(s_u*(qu-128) + s_v*(qv-128)) + b2 ----------
// 16-lane group per edge, 4 edges per group-iteration. Lane q reads bytes = cols {j*16+q};
// j<4 -> scale .x, j>=4 -> scale .y.
__global__ __launch_bounds__(256) void edge_score_i8(
    const uint8_t* __restrict__ u8, const uint8_t* __restrict__ v8,
    const float* __restrict__ su, const float* __restrict__ sv,  // [Nn][2]
    const int* __restrict__ src, const int* __restrict__ dst,
    const float* __restrict__ w2, const float* __restrict__ b2p,
    float* __restrict__ out, int E)
{
  const int t  = threadIdx.x;
  const int l  = t & 63;
  const int q  = l & 15;
  const int lg = l >> 4;

  float w2r[8];
#pragma unroll
  for (int j = 0; j < 8; ++j) w2r[j] = w2[j * 16 + q];
  const float b2 = b2p[0];

  const int gw = blockIdx.x * 4 + (t >> 6);
  const int TW = gridDim.x * 4;
  const float2* su2 = (const float2*)su;
  const float2* sv2 = (const float2*)sv;

  for (int base = gw * 16; base < E; base += TW * 16) {
    int e[4]; bool ok[4];
    uint2 ug[4], vg[4];
    float2 ss[4], sd[4];
#pragma unroll
    for (int i = 0; i < 4; ++i) {
      e[i]  = base + i * 4 + lg;
      ok[i] = e[i] < E;
      const int eS = ok[i] ? e[i] : 0;
      const int s = src[eS];
      const int d = dst[eS];
      ug[i] = *(const uint2*)(u8 + (size_t)s * 128 + q * 8);
      vg[i] = *(const uint2*)(v8 + (size_t)d * 128 + q * 8);
      ss[i] = su2[s];
      sd[i] = sv2[d];
    }
#pragma unroll
    for (int i = 0; i < 4; ++i) {
      const uint32_t ux = ug[i].x, uy = ug[i].y;
      const uint32_t vx = vg[i].x, vy = vg[i].y;
      const float bse0 = -128.0f * (ss[i].x + sd[i].x);
      const float bse1 = -128.0f * (ss[i].y + sd[i].y);
      float acc = 0.f;
#pragma unroll
      for (int j = 0; j < 4; ++j) {
        const float cu = (float)((ux >> (8 * j)) & 0xffu);   // v_cvt_f32_ubyteN
        const float cv = (float)((vx >> (8 * j)) & 0xffu);
        float x = fmaf(cu, ss[i].x, fmaf(cv, sd[i].x, bse0));
        x = fmaxf(x, 0.f);
        acc = fmaf(x, w2r[j], acc);
      }
#pragma unroll
      for (int j = 0; j < 4; ++j) {
        const float cu = (float)((uy >> (8 * j)) & 0xffu);
        const float cv = (float)((vy >> (8 * j)) & 0xffu);
        float x = fmaf(cu, ss[i].y, fmaf(cv, sd[i].y, bse1));
        x = fmaxf(x, 0.f);
        acc = fmaf(x, w2r[4 + j], acc);
      }
      acc += __shfl_xor(acc, 1);
      acc += __shfl_xor(acc, 2);
      acc += __shfl_xor(acc, 4);
      acc += __shfl_xor(acc, 8);
      if (q == 0 && ok[i]) out[e[i]] = acc + b2;
    }
  }
}

extern "C" void kernel_launch(void* const* d_in, const int* in_sizes, int n_in,
                              void* d_out, int out_size, void* d_ws, size_t ws_size,
                              hipStream_t stream) {
  const float* h   = (const float*)d_in[0];
  const int*   src = (const int*)d_in[1];
  const int*   dst = (const int*)d_in[2];
  const float* W1  = (const float*)d_in[3];
  const float* b1  = (const float*)d_in[4];
  const float* w2  = (const float*)d_in[5];
  const float* b2  = (const float*)d_in[6];
  float* out = (float*)d_out;

  const int nh = in_sizes[0];
  const int Nn = nh / 128;
  const int E  = in_sizes[1];

  uint8_t* ws = (uint8_t*)d_ws;
  int4*  blob = (int4*)ws;                                          // 64 KiB
  size_t off  = 65536;
  float* su   = (float*)(ws + off);  off += (size_t)Nn * 8;
  off = (off + 511) & ~(size_t)511;
  float* sv   = (float*)(ws + off);  off += (size_t)Nn * 8;
  off = (off + 511) & ~(size_t)511;
  uint8_t* u8 = ws + off;            off += (size_t)Nn * 128;
  uint8_t* v8 = ws + off;

  hipLaunchKernelGGL(repack_W1, dim3(16), dim3(256), 0, stream, W1, blob);

  const int NT      = (Nn + 15) / 16;
  const int nblocks = 1024;                    // 4 blocks/CU resident (persistent)
  const int niter   = (NT + nblocks - 1) / nblocks;
  hipLaunchKernelGGL(node_uv, dim3(nblocks), dim3(256), 0, stream,
                     h, blob, b1, u8, v8, su, sv, Nn, NT, nblocks, niter);

  hipLaunchKernelGGL(edge_score_i8, dim3(2048), dim3(256), 0, stream,
                     u8, v8, su, sv, src, dst, w2, b2, out, E);
}